// Round 2
// baseline (248.884 us; speedup 1.0000x reference)
//
#include <hip/hip_runtime.h>
#include <hip/hip_bf16.h>
#include <stdint.h>

#define N_OUT 512
#define N_IN 64
#define D_TOT 576               // N_IN + N_OUT
#define BM 64                   // batch rows per block
#define ROW_BYTES (D_TOT * 2)   // 1152 bytes per LDS row (bf16)
#define NWAVES 8                // 512 threads per block

typedef __attribute__((ext_vector_type(8))) short short8_t;   // 8 x bf16
typedef __attribute__((ext_vector_type(4))) float f32x4;
typedef unsigned short u16;

// HW bf16 conversion (RNE) — compiler emits v_cvt_pk_bf16_f32 for pairs
__device__ __forceinline__ u16 f2bf(float f) {
    __hip_bfloat16 h = __float2bfloat16(f);
    return *reinterpret_cast<u16*>(&h);
}
__device__ __forceinline__ float bf2f(u16 u) {
    union { uint32_t u; float f; } v;
    v.u = ((uint32_t)u) << 16;
    return v.f;
}

// Prep: masked bf16 weights, k-major fragment layout:
//   dst[((kk*4 + lg) * 512 + col) * 8 + j]  holds W[col][kk*32 + lg*8 + j]
// so a wave's B-fragment load (16 cols x 16B) is 4 contiguous 256B segments.
__global__ void prep_weights_kernel(const float* __restrict__ PA,
                                    const float* __restrict__ PB,
                                    u16* __restrict__ WA,
                                    u16* __restrict__ WB) {
    const int col = blockIdx.x;          // output index i in [0,512)
    const int lim = N_IN + col;          // valid k < lim
    const float* pa = PA + (size_t)col * D_TOT;
    const float* pb = PB + (size_t)col * D_TOT;
    for (int k = threadIdx.x; k < D_TOT; k += blockDim.x) {
        int kk = k >> 5, lg = (k >> 3) & 3, j = k & 7;
        size_t dst = ((size_t)(kk * 4 + lg) * N_OUT + col) * 8 + j;
        bool valid = (k < lim);
        WA[dst] = valid ? f2bf(pa[k]) : (u16)0;
        WB[dst] = valid ? f2bf(pb[k]) : (u16)0;
    }
}

// Main fused kernel.
// 512 threads (8 waves). BM=64 rows staged to LDS as bf16 (XOR-swizzled).
// Wave w owns column groups {w, 15-w} (32 cols each) -> 21 K-steps each
// (causal mask: group g needs ksteps = 3+g of K=32). No barriers in K loop.
// LDS 75776 B -> 2 blocks/CU -> 16 waves/CU (50% occupancy).
__global__ __launch_bounds__(512, 4)
void maf_main_kernel(const float* __restrict__ X,
                     const float* __restrict__ Cc,
                     const u16* __restrict__ WA,
                     const u16* __restrict__ WB,
                     float* __restrict__ Z,
                     float* __restrict__ LD) {
    extern __shared__ char smem[];
    char* xt = smem;                                   // [64][1152] bytes, swizzled
    float* ldsum = (float*)(smem + BM * ROW_BYTES);    // [8][64]

    const int tid = threadIdx.x;
    const int r0 = blockIdx.x * BM;

    // ---- stage c (k in [0,64)) : 512 chunks of 8 f32, 1 per thread ----
    {
        int row = tid >> 3, cc = tid & 7;
        const float* src = Cc + (size_t)(r0 + row) * N_IN + cc * 8;
        f32x4 v0 = *(const f32x4*)src;
        f32x4 v1 = *(const f32x4*)(src + 4);
        short8_t p;
        p[0] = (short)f2bf(v0[0]); p[1] = (short)f2bf(v0[1]);
        p[2] = (short)f2bf(v0[2]); p[3] = (short)f2bf(v0[3]);
        p[4] = (short)f2bf(v1[0]); p[5] = (short)f2bf(v1[1]);
        p[6] = (short)f2bf(v1[2]); p[7] = (short)f2bf(v1[3]);
        int addr = (row * ROW_BYTES + cc * 16) ^ ((row & 7) << 4);
        *(short8_t*)(xt + addr) = p;
    }
    // ---- stage X (k in [64,576)) : 4096 chunks, 8 per thread ----
    #pragma unroll
    for (int i = 0; i < 8; ++i) {
        int id = tid + i * 512;
        int row = id >> 6, xc = id & 63;
        const float* src = X + (size_t)(r0 + row) * N_OUT + xc * 8;
        f32x4 v0 = *(const f32x4*)src;
        f32x4 v1 = *(const f32x4*)(src + 4);
        short8_t p;
        p[0] = (short)f2bf(v0[0]); p[1] = (short)f2bf(v0[1]);
        p[2] = (short)f2bf(v0[2]); p[3] = (short)f2bf(v0[3]);
        p[4] = (short)f2bf(v1[0]); p[5] = (short)f2bf(v1[1]);
        p[6] = (short)f2bf(v1[2]); p[7] = (short)f2bf(v1[3]);
        int addr = (row * ROW_BYTES + (8 + xc) * 16) ^ ((row & 7) << 4);
        *(short8_t*)(xt + addr) = p;
    }
    __syncthreads();

    const int wid = tid >> 6;
    const int lane = tid & 63;
    const int lr = lane & 15;   // fragment row (A) / col (B,C)
    const int lg = lane >> 4;   // k sub-block (A,B) / row quad (C)

    float part[4][4];           // per-lane log_det partials [m][j]
    #pragma unroll
    for (int m = 0; m < 4; ++m)
        #pragma unroll
        for (int j = 0; j < 4; ++j) part[m][j] = 0.0f;

    const int groups[2] = { wid, 15 - wid };   // 3+w + 18-w = 21 ksteps, balanced

    #pragma unroll
    for (int gi = 0; gi < 2; ++gi) {
        const int g = groups[gi];
        const int c0 = g << 5;          // first column of group
        const int ksteps = 3 + g;       // causal mask: k < 64 + col

        f32x4 accA[4][2], accB[4][2];
        #pragma unroll
        for (int m = 0; m < 4; ++m)
            #pragma unroll
            for (int n = 0; n < 2; ++n) {
                accA[m][n] = (f32x4)(0.0f);
                accB[m][n] = (f32x4)(0.0f);
            }

        #pragma unroll 3
        for (int kk = 0; kk < ksteps; ++kk) {
            const int kb = kk * 64 + lg * 16;   // byte offset of this lane's k-slice
            short8_t a[4];
            #pragma unroll
            for (int m = 0; m < 4; ++m) {
                int row = (m << 4) + lr;
                int addr = (row * ROW_BYTES + kb) ^ ((row & 7) << 4);
                a[m] = *(const short8_t*)(xt + addr);
            }
            short8_t ba[2], bb[2];
            const size_t wbase = (size_t)((kk << 2) + lg) * N_OUT + c0 + lr;
            #pragma unroll
            for (int n = 0; n < 2; ++n) {
                size_t off = (wbase + (n << 4)) * 8;
                ba[n] = *(const short8_t*)(WA + off);
                bb[n] = *(const short8_t*)(WB + off);
            }
            #pragma unroll
            for (int m = 0; m < 4; ++m) {
                #pragma unroll
                for (int n = 0; n < 2; ++n) {
                    accA[m][n] = __builtin_amdgcn_mfma_f32_16x16x32_bf16(a[m], ba[n], accA[m][n], 0, 0, 0);
                    accB[m][n] = __builtin_amdgcn_mfma_f32_16x16x32_bf16(a[m], bb[n], accB[m][n], 0, 0, 0);
                }
            }
        }

        // ---- epilogue for this 32-col group ----
        // C/D layout (verified m89/m91): col = lane&15, row = (lane>>4)*4 + reg
        #pragma unroll
        for (int m = 0; m < 4; ++m) {
            #pragma unroll
            for (int n = 0; n < 2; ++n) {
                int col = c0 + (n << 4) + lr;
                #pragma unroll
                for (int j = 0; j < 4; ++j) {
                    int row = (m << 4) + (lg << 2) + j;
                    float Av = accA[m][n][j];
                    float Bv = accB[m][n][j];
                    int xaddr = (row * ROW_BYTES + (N_IN + col) * 2) ^ ((row & 7) << 4);
                    float Xf = bf2f(*(const u16*)(xt + xaddr));
                    Z[(size_t)(r0 + row) * N_OUT + col] = Xf * __expf(Av) + Bv;
                    part[m][j] += Av;
                }
            }
        }
    }

    // ---- log_det: reduce across the 16 lanes that share rows (same lg) ----
    #pragma unroll
    for (int m = 0; m < 4; ++m) {
        #pragma unroll
        for (int j = 0; j < 4; ++j) {
            float v = part[m][j];
            v += __shfl_xor(v, 1);
            v += __shfl_xor(v, 2);
            v += __shfl_xor(v, 4);
            v += __shfl_xor(v, 8);
            if (lr == 0) ldsum[(wid << 6) + (m << 4) + (lg << 2) + j] = v;
        }
    }
    __syncthreads();
    if (tid < 64) {
        float s = 0.0f;
        #pragma unroll
        for (int w = 0; w < NWAVES; ++w) s += ldsum[(w << 6) + tid];
        LD[(size_t)r0 + tid] = s;
    }
}

extern "C" void kernel_launch(void* const* d_in, const int* in_sizes, int n_in,
                              void* d_out, int out_size, void* d_ws, size_t ws_size,
                              hipStream_t stream) {
    const float* X  = (const float*)d_in[0];
    const float* Cc = (const float*)d_in[1];
    const float* PA = (const float*)d_in[2];
    const float* PB = (const float*)d_in[3];

    u16* WA = (u16*)d_ws;                          // 512*576*2 bytes (k-major)
    u16* WB = WA + (size_t)N_OUT * D_TOT;          // another 512*576*2

    float* Z  = (float*)d_out;
    const size_t batch = (size_t)in_sizes[0] / N_OUT;   // 131072
    float* LD = Z + batch * N_OUT;

    prep_weights_kernel<<<N_OUT, 256, 0, stream>>>(PA, PB, WA, WB);

    const size_t lds_bytes = (size_t)BM * ROW_BYTES + NWAVES * 64 * sizeof(float); // 75776
    (void)hipFuncSetAttribute((const void*)maf_main_kernel,
                              hipFuncAttributeMaxDynamicSharedMemorySize,
                              (int)lds_bytes);
    const int grid = (int)(batch / BM);            // 2048
    maf_main_kernel<<<grid, 512, lds_bytes, stream>>>(X, Cc, WA, WB, Z, LD);
}

// Round 4
// 234.251 us; speedup vs baseline: 1.0625x; 1.0625x over previous
//
#include <hip/hip_runtime.h>
#include <hip/hip_bf16.h>
#include <stdint.h>

#define N_OUT 512
#define N_IN 64
#define D_TOT 576               // N_IN + N_OUT
#define BM 64                   // batch rows per block
#define ROW_BYTES (D_TOT * 2)   // 1152 bytes per LDS row (bf16)
#define NWAVES 8                // 512 threads per block

typedef __attribute__((ext_vector_type(8))) short short8_t;   // 8 x bf16
typedef __attribute__((ext_vector_type(4))) float f32x4;
typedef unsigned short u16;

// HW bf16 conversion (RNE) — compiler emits v_cvt_pk_bf16_f32 for pairs
__device__ __forceinline__ u16 f2bf(float f) {
    __hip_bfloat16 h = __float2bfloat16(f);
    return *reinterpret_cast<u16*>(&h);
}
__device__ __forceinline__ float bf2f(u16 u) {
    union { uint32_t u; float f; } v;
    v.u = ((uint32_t)u) << 16;
    return v.f;
}

// Prep: masked bf16 weights, k-major fragment layout:
//   dst[((kk*4 + lg) * 512 + col) * 8 + j]  holds W[col][kk*32 + lg*8 + j]
// so a wave's B-fragment load (16 cols x 16B) is 4 contiguous 256B segments.
__global__ void prep_weights_kernel(const float* __restrict__ PA,
                                    const float* __restrict__ PB,
                                    u16* __restrict__ WA,
                                    u16* __restrict__ WB) {
    const int col = blockIdx.x;          // output index i in [0,512)
    const int lim = N_IN + col;          // valid k < lim
    const float* pa = PA + (size_t)col * D_TOT;
    const float* pb = PB + (size_t)col * D_TOT;
    for (int k = threadIdx.x; k < D_TOT; k += blockDim.x) {
        int kk = k >> 5, lg = (k >> 3) & 3, j = k & 7;
        size_t dst = ((size_t)(kk * 4 + lg) * N_OUT + col) * 8 + j;
        bool valid = (k < lim);
        WA[dst] = valid ? f2bf(pa[k]) : (u16)0;
        WB[dst] = valid ? f2bf(pb[k]) : (u16)0;
    }
}

// Main fused kernel.
// 512 threads (8 waves). BM=64 rows staged to LDS as bf16 (XOR-swizzled).
// Wave w owns column groups {w, 15-w} (32 cols each) -> 21 K-steps each
// (causal mask: group g needs ksteps = 3+g of K=32). No barriers in K loop.
// LDS 75776 B -> 2 blocks/CU; launch_bounds(512,2) -> 128-VGPR cap (no spill).
__global__ __launch_bounds__(512, 2)
void maf_main_kernel(const float* __restrict__ X,
                     const float* __restrict__ Cc,
                     const u16* __restrict__ WA,
                     const u16* __restrict__ WB,
                     float* __restrict__ Z,
                     float* __restrict__ LD) {
    extern __shared__ char smem[];
    char* xt = smem;                                   // [64][1152] bytes, swizzled
    float* ldsum = (float*)(smem + BM * ROW_BYTES);    // [8][64]

    const int tid = threadIdx.x;
    const int r0 = blockIdx.x * BM;

    // ---- stage c (k in [0,64)) : 512 chunks of 8 f32, 1 per thread ----
    {
        int row = tid >> 3, cc = tid & 7;
        const float* src = Cc + (size_t)(r0 + row) * N_IN + cc * 8;
        f32x4 v0 = *(const f32x4*)src;
        f32x4 v1 = *(const f32x4*)(src + 4);
        short8_t p;
        p[0] = (short)f2bf(v0[0]); p[1] = (short)f2bf(v0[1]);
        p[2] = (short)f2bf(v0[2]); p[3] = (short)f2bf(v0[3]);
        p[4] = (short)f2bf(v1[0]); p[5] = (short)f2bf(v1[1]);
        p[6] = (short)f2bf(v1[2]); p[7] = (short)f2bf(v1[3]);
        int addr = (row * ROW_BYTES + cc * 16) ^ ((row & 7) << 4);
        *(short8_t*)(xt + addr) = p;
    }
    // ---- stage X (k in [64,576)) : 4096 chunks, 8 per thread ----
    #pragma unroll
    for (int i = 0; i < 8; ++i) {
        int id = tid + i * 512;
        int row = id >> 6, xc = id & 63;
        const float* src = X + (size_t)(r0 + row) * N_OUT + xc * 8;
        f32x4 v0 = *(const f32x4*)src;
        f32x4 v1 = *(const f32x4*)(src + 4);
        short8_t p;
        p[0] = (short)f2bf(v0[0]); p[1] = (short)f2bf(v0[1]);
        p[2] = (short)f2bf(v0[2]); p[3] = (short)f2bf(v0[3]);
        p[4] = (short)f2bf(v1[0]); p[5] = (short)f2bf(v1[1]);
        p[6] = (short)f2bf(v1[2]); p[7] = (short)f2bf(v1[3]);
        int addr = (row * ROW_BYTES + (8 + xc) * 16) ^ ((row & 7) << 4);
        *(short8_t*)(xt + addr) = p;
    }
    __syncthreads();

    const int wid = tid >> 6;
    const int lane = tid & 63;
    const int lr = lane & 15;   // fragment row (A) / col (B,C)
    const int lg = lane >> 4;   // k sub-block (A,B) / row quad (C)

    float part[4][4];           // per-lane log_det partials [m][j]
    #pragma unroll
    for (int m = 0; m < 4; ++m)
        #pragma unroll
        for (int j = 0; j < 4; ++j) part[m][j] = 0.0f;

    const int groups[2] = { wid, 15 - wid };   // 3+w + 18-w = 21 ksteps, balanced

    #pragma unroll
    for (int gi = 0; gi < 2; ++gi) {
        const int g = groups[gi];
        const int c0 = g << 5;          // first column of group
        const int ksteps = 3 + g;       // causal mask: k < 64 + col

        f32x4 accA[4][2], accB[4][2];
        #pragma unroll
        for (int m = 0; m < 4; ++m)
            #pragma unroll
            for (int n = 0; n < 2; ++n) {
                accA[m][n] = (f32x4)(0.0f);
                accB[m][n] = (f32x4)(0.0f);
            }

        #pragma unroll 3
        for (int kk = 0; kk < ksteps; ++kk) {
            const int kb = kk * 64 + lg * 16;   // byte offset of this lane's k-slice
            short8_t a[4];
            #pragma unroll
            for (int m = 0; m < 4; ++m) {
                int row = (m << 4) + lr;
                int addr = (row * ROW_BYTES + kb) ^ ((row & 7) << 4);
                a[m] = *(const short8_t*)(xt + addr);
            }
            short8_t ba[2], bb[2];
            const size_t wbase = (size_t)((kk << 2) + lg) * N_OUT + c0 + lr;
            #pragma unroll
            for (int n = 0; n < 2; ++n) {
                size_t off = (wbase + (n << 4)) * 8;
                ba[n] = *(const short8_t*)(WA + off);
                bb[n] = *(const short8_t*)(WB + off);
            }
            #pragma unroll
            for (int m = 0; m < 4; ++m) {
                #pragma unroll
                for (int n = 0; n < 2; ++n) {
                    accA[m][n] = __builtin_amdgcn_mfma_f32_16x16x32_bf16(a[m], ba[n], accA[m][n], 0, 0, 0);
                    accB[m][n] = __builtin_amdgcn_mfma_f32_16x16x32_bf16(a[m], bb[n], accB[m][n], 0, 0, 0);
                }
            }
        }

        // ---- epilogue for this 32-col group ----
        // C/D layout (verified m89/m91): col = lane&15, row = (lane>>4)*4 + reg
        #pragma unroll
        for (int m = 0; m < 4; ++m) {
            #pragma unroll
            for (int n = 0; n < 2; ++n) {
                int col = c0 + (n << 4) + lr;
                #pragma unroll
                for (int j = 0; j < 4; ++j) {
                    int row = (m << 4) + (lg << 2) + j;
                    float Av = accA[m][n][j];
                    float Bv = accB[m][n][j];
                    int xaddr = (row * ROW_BYTES + (N_IN + col) * 2) ^ ((row & 7) << 4);
                    float Xf = bf2f(*(const u16*)(xt + xaddr));
                    Z[(size_t)(r0 + row) * N_OUT + col] = Xf * __expf(Av) + Bv;
                    part[m][j] += Av;
                }
            }
        }
    }

    // ---- log_det: reduce across the 16 lanes that share rows (same lg) ----
    #pragma unroll
    for (int m = 0; m < 4; ++m) {
        #pragma unroll
        for (int j = 0; j < 4; ++j) {
            float v = part[m][j];
            v += __shfl_xor(v, 1);
            v += __shfl_xor(v, 2);
            v += __shfl_xor(v, 4);
            v += __shfl_xor(v, 8);
            if (lr == 0) ldsum[(wid << 6) + (m << 4) + (lg << 2) + j] = v;
        }
    }
    __syncthreads();
    if (tid < 64) {
        float s = 0.0f;
        #pragma unroll
        for (int w = 0; w < NWAVES; ++w) s += ldsum[(w << 6) + tid];
        LD[(size_t)r0 + tid] = s;
    }
}

extern "C" void kernel_launch(void* const* d_in, const int* in_sizes, int n_in,
                              void* d_out, int out_size, void* d_ws, size_t ws_size,
                              hipStream_t stream) {
    const float* X  = (const float*)d_in[0];
    const float* Cc = (const float*)d_in[1];
    const float* PA = (const float*)d_in[2];
    const float* PB = (const float*)d_in[3];

    u16* WA = (u16*)d_ws;                          // 512*576*2 bytes (k-major)
    u16* WB = WA + (size_t)N_OUT * D_TOT;          // another 512*576*2

    float* Z  = (float*)d_out;
    const size_t batch = (size_t)in_sizes[0] / N_OUT;   // 131072
    float* LD = Z + batch * N_OUT;

    prep_weights_kernel<<<N_OUT, 256, 0, stream>>>(PA, PB, WA, WB);

    const size_t lds_bytes = (size_t)BM * ROW_BYTES + NWAVES * 64 * sizeof(float); // 75776
    (void)hipFuncSetAttribute((const void*)maf_main_kernel,
                              hipFuncAttributeMaxDynamicSharedMemorySize,
                              (int)lds_bytes);
    const int grid = (int)(batch / BM);            // 2048
    maf_main_kernel<<<grid, 512, lds_bytes, stream>>>(X, Cc, WA, WB, Z, LD);
}

// Round 5
// 223.468 us; speedup vs baseline: 1.1137x; 1.0483x over previous
//
#include <hip/hip_runtime.h>
#include <hip/hip_bf16.h>
#include <stdint.h>

#define N_OUT 512
#define N_IN 64
#define D_TOT 576               // N_IN + N_OUT
#define BM 32                   // batch rows per block
#define ROW_BYTES (D_TOT * 2)   // 1152 bytes per LDS row (bf16)
#define NWAVES 4                // 256 threads per block

typedef __attribute__((ext_vector_type(8))) short short8_t;   // 8 x bf16
typedef __attribute__((ext_vector_type(4))) float f32x4;
typedef unsigned short u16;

// HW bf16 conversion (RNE)
__device__ __forceinline__ u16 f2bf(float f) {
    __hip_bfloat16 h = __float2bfloat16(f);
    return *reinterpret_cast<u16*>(&h);
}
__device__ __forceinline__ float bf2f(u16 u) {
    union { uint32_t u; float f; } v;
    v.u = ((uint32_t)u) << 16;
    return v.f;
}

// Prep: masked bf16 weights, k-major fragment layout:
//   dst[((kk*4 + lg) * 512 + col) * 8 + j]  holds W[col][kk*32 + lg*8 + j]
// so a wave's B-fragment load (16 cols x 16B) is 4 contiguous 256B segments.
__global__ void prep_weights_kernel(const float* __restrict__ PA,
                                    const float* __restrict__ PB,
                                    u16* __restrict__ WA,
                                    u16* __restrict__ WB) {
    const int col = blockIdx.x;          // output index i in [0,512)
    const int lim = N_IN + col;          // valid k < lim
    const float* pa = PA + (size_t)col * D_TOT;
    const float* pb = PB + (size_t)col * D_TOT;
    for (int k = threadIdx.x; k < D_TOT; k += blockDim.x) {
        int kk = k >> 5, lg = (k >> 3) & 3, j = k & 7;
        size_t dst = ((size_t)(kk * 4 + lg) * N_OUT + col) * 8 + j;
        bool valid = (k < lim);
        WA[dst] = valid ? f2bf(pa[k]) : (u16)0;
        WB[dst] = valid ? f2bf(pb[k]) : (u16)0;
    }
}

// Main fused kernel.
// 256 threads (4 waves). BM=32 rows staged to LDS as bf16 (XOR-swizzled).
// Wave w owns column groups {w, 7-w, 8+w, 15-w} (32 cols each) -> 42 K-steps
// each (causal: group g needs 3+g K-steps of 32). No barriers in K loop.
// LDS 37376 B -> 4 blocks/CU; launch_bounds(256,4) -> 128-VGPR cap.
__global__ __launch_bounds__(256, 4)
void maf_main_kernel(const float* __restrict__ X,
                     const float* __restrict__ Cc,
                     const u16* __restrict__ WA,
                     const u16* __restrict__ WB,
                     float* __restrict__ Z,
                     float* __restrict__ LD) {
    extern __shared__ char smem[];
    char* xt = smem;                                   // [32][1152] bytes, swizzled
    float* ldsum = (float*)(smem + BM * ROW_BYTES);    // [4][32]

    const int tid = threadIdx.x;
    const int r0 = blockIdx.x * BM;

    // ---- stage c (k in [0,64)) : 256 chunks of 8 f32, 1 per thread ----
    {
        int row = tid >> 3, cc = tid & 7;
        const float* src = Cc + (size_t)(r0 + row) * N_IN + cc * 8;
        f32x4 v0 = *(const f32x4*)src;
        f32x4 v1 = *(const f32x4*)(src + 4);
        short8_t p;
        p[0] = (short)f2bf(v0[0]); p[1] = (short)f2bf(v0[1]);
        p[2] = (short)f2bf(v0[2]); p[3] = (short)f2bf(v0[3]);
        p[4] = (short)f2bf(v1[0]); p[5] = (short)f2bf(v1[1]);
        p[6] = (short)f2bf(v1[2]); p[7] = (short)f2bf(v1[3]);
        int addr = (row * ROW_BYTES + cc * 16) ^ ((row & 7) << 4);
        *(short8_t*)(xt + addr) = p;
    }
    // ---- stage X (k in [64,576)) : 2048 chunks, 8 per thread ----
    #pragma unroll
    for (int i = 0; i < 8; ++i) {
        int id = tid + i * 256;
        int row = id >> 6, xc = id & 63;
        const float* src = X + (size_t)(r0 + row) * N_OUT + xc * 8;
        f32x4 v0 = *(const f32x4*)src;
        f32x4 v1 = *(const f32x4*)(src + 4);
        short8_t p;
        p[0] = (short)f2bf(v0[0]); p[1] = (short)f2bf(v0[1]);
        p[2] = (short)f2bf(v0[2]); p[3] = (short)f2bf(v0[3]);
        p[4] = (short)f2bf(v1[0]); p[5] = (short)f2bf(v1[1]);
        p[6] = (short)f2bf(v1[2]); p[7] = (short)f2bf(v1[3]);
        int addr = (row * ROW_BYTES + (8 + xc) * 16) ^ ((row & 7) << 4);
        *(short8_t*)(xt + addr) = p;
    }
    __syncthreads();

    const int wid = tid >> 6;
    const int lane = tid & 63;
    const int lr = lane & 15;   // fragment row (A) / col (B,C)
    const int lg = lane >> 4;   // k sub-block (A,B) / row quad (C)

    float part[2][4];           // per-lane log_det partials [m][j]
    #pragma unroll
    for (int m = 0; m < 2; ++m)
        #pragma unroll
        for (int j = 0; j < 4; ++j) part[m][j] = 0.0f;

    const int groups[4] = { wid, 7 - wid, 8 + wid, 15 - wid };  // 42 ksteps total

    #pragma unroll
    for (int gi = 0; gi < 4; ++gi) {
        const int g = groups[gi];
        const int c0 = g << 5;          // first column of group
        const int ksteps = 3 + g;       // causal mask: k < 64 + col

        f32x4 accA[2][2], accB[2][2];
        #pragma unroll
        for (int m = 0; m < 2; ++m)
            #pragma unroll
            for (int n = 0; n < 2; ++n) {
                accA[m][n] = (f32x4)(0.0f);
                accB[m][n] = (f32x4)(0.0f);
            }

        #pragma unroll 3
        for (int kk = 0; kk < ksteps; ++kk) {
            const int kb = kk * 64 + lg * 16;   // byte offset of this lane's k-slice
            short8_t a[2];
            #pragma unroll
            for (int m = 0; m < 2; ++m) {
                int row = (m << 4) + lr;
                int addr = (row * ROW_BYTES + kb) ^ ((row & 7) << 4);
                a[m] = *(const short8_t*)(xt + addr);
            }
            short8_t ba[2], bb[2];
            const size_t wbase = (size_t)((kk << 2) + lg) * N_OUT + c0 + lr;
            #pragma unroll
            for (int n = 0; n < 2; ++n) {
                size_t off = (wbase + (n << 4)) * 8;
                ba[n] = *(const short8_t*)(WA + off);
                bb[n] = *(const short8_t*)(WB + off);
            }
            #pragma unroll
            for (int m = 0; m < 2; ++m) {
                #pragma unroll
                for (int n = 0; n < 2; ++n) {
                    accA[m][n] = __builtin_amdgcn_mfma_f32_16x16x32_bf16(a[m], ba[n], accA[m][n], 0, 0, 0);
                    accB[m][n] = __builtin_amdgcn_mfma_f32_16x16x32_bf16(a[m], bb[n], accB[m][n], 0, 0, 0);
                }
            }
        }

        // ---- epilogue for this 32-col group ----
        // C/D layout (verified m89/m91): col = lane&15, row = (lane>>4)*4 + reg
        #pragma unroll
        for (int m = 0; m < 2; ++m) {
            #pragma unroll
            for (int n = 0; n < 2; ++n) {
                int col = c0 + (n << 4) + lr;
                #pragma unroll
                for (int j = 0; j < 4; ++j) {
                    int row = (m << 4) + (lg << 2) + j;
                    float Av = accA[m][n][j];
                    float Bv = accB[m][n][j];
                    int xaddr = (row * ROW_BYTES + (N_IN + col) * 2) ^ ((row & 7) << 4);
                    float Xf = bf2f(*(const u16*)(xt + xaddr));
                    Z[(size_t)(r0 + row) * N_OUT + col] = Xf * __expf(Av) + Bv;
                    part[m][j] += Av;
                }
            }
        }
    }

    // ---- log_det: reduce across the 16 lanes that share rows (same lg) ----
    #pragma unroll
    for (int m = 0; m < 2; ++m) {
        #pragma unroll
        for (int j = 0; j < 4; ++j) {
            float v = part[m][j];
            v += __shfl_xor(v, 1);
            v += __shfl_xor(v, 2);
            v += __shfl_xor(v, 4);
            v += __shfl_xor(v, 8);
            if (lr == 0) ldsum[(wid << 5) + (m << 4) + (lg << 2) + j] = v;
        }
    }
    __syncthreads();
    if (tid < BM) {
        float s = 0.0f;
        #pragma unroll
        for (int w = 0; w < NWAVES; ++w) s += ldsum[(w << 5) + tid];
        LD[(size_t)r0 + tid] = s;
    }
}

extern "C" void kernel_launch(void* const* d_in, const int* in_sizes, int n_in,
                              void* d_out, int out_size, void* d_ws, size_t ws_size,
                              hipStream_t stream) {
    const float* X  = (const float*)d_in[0];
    const float* Cc = (const float*)d_in[1];
    const float* PA = (const float*)d_in[2];
    const float* PB = (const float*)d_in[3];

    u16* WA = (u16*)d_ws;                          // 512*576*2 bytes (k-major)
    u16* WB = WA + (size_t)N_OUT * D_TOT;          // another 512*576*2

    float* Z  = (float*)d_out;
    const size_t batch = (size_t)in_sizes[0] / N_OUT;   // 131072
    float* LD = Z + batch * N_OUT;

    prep_weights_kernel<<<N_OUT, 256, 0, stream>>>(PA, PB, WA, WB);

    const size_t lds_bytes = (size_t)BM * ROW_BYTES + NWAVES * BM * sizeof(float); // 37376
    const int grid = (int)(batch / BM);            // 4096
    maf_main_kernel<<<grid, 256, lds_bytes, stream>>>(X, Cc, WA, WB, Z, LD);
}

// Round 6
// 212.486 us; speedup vs baseline: 1.1713x; 1.0517x over previous
//
#include <hip/hip_runtime.h>
#include <hip/hip_bf16.h>
#include <stdint.h>

#define N_OUT 512
#define N_IN 64
#define D_TOT 576               // N_IN + N_OUT
#define BM 32                   // batch rows per block
#define ROW_BYTES (D_TOT * 2)   // 1152 bytes per LDS row (bf16)
#define NWAVES 4                // 256 threads per block

typedef __attribute__((ext_vector_type(8))) short short8_t;   // 8 x bf16
typedef __attribute__((ext_vector_type(4))) float f32x4;
typedef unsigned short u16;

// HW bf16 conversion (RNE)
__device__ __forceinline__ u16 f2bf(float f) {
    __hip_bfloat16 h = __float2bfloat16(f);
    return *reinterpret_cast<u16*>(&h);
}
__device__ __forceinline__ float bf2f(u16 u) {
    union { uint32_t u; float f; } v;
    v.u = ((uint32_t)u) << 16;
    return v.f;
}

// Prep: masked bf16 weights, k-major fragment layout:
//   dst[((kk*4 + lg) * 512 + col) * 8 + j]  holds W[col][kk*32 + lg*8 + j]
// so a wave's B-fragment load (16 cols x 16B) is 4 contiguous 256B segments.
__global__ void prep_weights_kernel(const float* __restrict__ PA,
                                    const float* __restrict__ PB,
                                    u16* __restrict__ WA,
                                    u16* __restrict__ WB) {
    const int col = blockIdx.x;          // output index i in [0,512)
    const int lim = N_IN + col;          // valid k < lim
    const float* pa = PA + (size_t)col * D_TOT;
    const float* pb = PB + (size_t)col * D_TOT;
    for (int k = threadIdx.x; k < D_TOT; k += blockDim.x) {
        int kk = k >> 5, lg = (k >> 3) & 3, j = k & 7;
        size_t dst = ((size_t)(kk * 4 + lg) * N_OUT + col) * 8 + j;
        bool valid = (k < lim);
        WA[dst] = valid ? f2bf(pa[k]) : (u16)0;
        WB[dst] = valid ? f2bf(pb[k]) : (u16)0;
    }
}

// Main fused kernel.
// 256 threads (4 waves). BM=32 rows staged to LDS as bf16 (XOR-swizzled).
// Wave w owns column groups {w, 7-w, 8+w, 15-w} (32 cols each) -> 42 K-steps
// each (causal: group g needs 3+g K-steps of 32). No barriers in K loop.
// LDS 37376 B -> 4 blocks/CU. NO min-waves arg: natural VGPR (~100) <= 128
// keeps 4 waves/SIMD without forcing a spill-inducing cap (R2/R5 lesson).
__global__ __launch_bounds__(256)
void maf_main_kernel(const float* __restrict__ X,
                     const float* __restrict__ Cc,
                     const u16* __restrict__ WA,
                     const u16* __restrict__ WB,
                     float* __restrict__ Z,
                     float* __restrict__ LD) {
    extern __shared__ char smem[];
    char* xt = smem;                                   // [32][1152] bytes, swizzled
    float* ldsum = (float*)(smem + BM * ROW_BYTES);    // [4][32]

    const int tid = threadIdx.x;
    const int r0 = blockIdx.x * BM;

    // ---- stage c (k in [0,64)) : 256 chunks of 8 f32, 1 per thread ----
    {
        int row = tid >> 3, cc = tid & 7;
        const float* src = Cc + (size_t)(r0 + row) * N_IN + cc * 8;
        f32x4 v0 = *(const f32x4*)src;
        f32x4 v1 = *(const f32x4*)(src + 4);
        short8_t p;
        p[0] = (short)f2bf(v0[0]); p[1] = (short)f2bf(v0[1]);
        p[2] = (short)f2bf(v0[2]); p[3] = (short)f2bf(v0[3]);
        p[4] = (short)f2bf(v1[0]); p[5] = (short)f2bf(v1[1]);
        p[6] = (short)f2bf(v1[2]); p[7] = (short)f2bf(v1[3]);
        int addr = (row * ROW_BYTES + cc * 16) ^ ((row & 7) << 4);
        *(short8_t*)(xt + addr) = p;
    }
    // ---- stage X (k in [64,576)) : 2048 chunks, 8 per thread ----
    #pragma unroll
    for (int i = 0; i < 8; ++i) {
        int id = tid + i * 256;
        int row = id >> 6, xc = id & 63;
        const float* src = X + (size_t)(r0 + row) * N_OUT + xc * 8;
        f32x4 v0 = *(const f32x4*)src;
        f32x4 v1 = *(const f32x4*)(src + 4);
        short8_t p;
        p[0] = (short)f2bf(v0[0]); p[1] = (short)f2bf(v0[1]);
        p[2] = (short)f2bf(v0[2]); p[3] = (short)f2bf(v0[3]);
        p[4] = (short)f2bf(v1[0]); p[5] = (short)f2bf(v1[1]);
        p[6] = (short)f2bf(v1[2]); p[7] = (short)f2bf(v1[3]);
        int addr = (row * ROW_BYTES + (8 + xc) * 16) ^ ((row & 7) << 4);
        *(short8_t*)(xt + addr) = p;
    }
    __syncthreads();

    const int wid = tid >> 6;
    const int lane = tid & 63;
    const int lr = lane & 15;   // fragment row (A) / col (B,C)
    const int lg = lane >> 4;   // k sub-block (A,B) / row quad (C)

    float part[2][4];           // per-lane log_det partials [m][j]
    #pragma unroll
    for (int m = 0; m < 2; ++m)
        #pragma unroll
        for (int j = 0; j < 4; ++j) part[m][j] = 0.0f;

    const int groups[4] = { wid, 7 - wid, 8 + wid, 15 - wid };  // 42 ksteps total

    #pragma unroll
    for (int gi = 0; gi < 4; ++gi) {
        const int g = groups[gi];
        const int c0 = g << 5;          // first column of group
        const int ksteps = 3 + g;       // causal mask: k < 64 + col

        f32x4 accA[2][2], accB[2][2];
        #pragma unroll
        for (int m = 0; m < 2; ++m)
            #pragma unroll
            for (int n = 0; n < 2; ++n) {
                accA[m][n] = (f32x4)(0.0f);
                accB[m][n] = (f32x4)(0.0f);
            }

        #pragma unroll 3
        for (int kk = 0; kk < ksteps; ++kk) {
            const int kb = kk * 64 + lg * 16;   // byte offset of this lane's k-slice
            short8_t a[2];
            #pragma unroll
            for (int m = 0; m < 2; ++m) {
                int row = (m << 4) + lr;
                int addr = (row * ROW_BYTES + kb) ^ ((row & 7) << 4);
                a[m] = *(const short8_t*)(xt + addr);
            }
            short8_t ba[2], bb[2];
            const size_t wbase = (size_t)((kk << 2) + lg) * N_OUT + c0 + lr;
            #pragma unroll
            for (int n = 0; n < 2; ++n) {
                size_t off = (wbase + (n << 4)) * 8;
                ba[n] = *(const short8_t*)(WA + off);
                bb[n] = *(const short8_t*)(WB + off);
            }
            #pragma unroll
            for (int m = 0; m < 2; ++m) {
                #pragma unroll
                for (int n = 0; n < 2; ++n) {
                    accA[m][n] = __builtin_amdgcn_mfma_f32_16x16x32_bf16(a[m], ba[n], accA[m][n], 0, 0, 0);
                    accB[m][n] = __builtin_amdgcn_mfma_f32_16x16x32_bf16(a[m], bb[n], accB[m][n], 0, 0, 0);
                }
            }
        }

        // ---- epilogue for this 32-col group ----
        // C/D layout (verified m89/m91): col = lane&15, row = (lane>>4)*4 + reg
        #pragma unroll
        for (int m = 0; m < 2; ++m) {
            #pragma unroll
            for (int n = 0; n < 2; ++n) {
                int col = c0 + (n << 4) + lr;
                #pragma unroll
                for (int j = 0; j < 4; ++j) {
                    int row = (m << 4) + (lg << 2) + j;
                    float Av = accA[m][n][j];
                    float Bv = accB[m][n][j];
                    int xaddr = (row * ROW_BYTES + (N_IN + col) * 2) ^ ((row & 7) << 4);
                    float Xf = bf2f(*(const u16*)(xt + xaddr));
                    Z[(size_t)(r0 + row) * N_OUT + col] = Xf * __expf(Av) + Bv;
                    part[m][j] += Av;
                }
            }
        }
    }

    // ---- log_det: reduce across the 16 lanes that share rows (same lg) ----
    #pragma unroll
    for (int m = 0; m < 2; ++m) {
        #pragma unroll
        for (int j = 0; j < 4; ++j) {
            float v = part[m][j];
            v += __shfl_xor(v, 1);
            v += __shfl_xor(v, 2);
            v += __shfl_xor(v, 4);
            v += __shfl_xor(v, 8);
            if (lr == 0) ldsum[(wid << 5) + (m << 4) + (lg << 2) + j] = v;
        }
    }
    __syncthreads();
    if (tid < BM) {
        float s = 0.0f;
        #pragma unroll
        for (int w = 0; w < NWAVES; ++w) s += ldsum[(w << 5) + tid];
        LD[(size_t)r0 + tid] = s;
    }
}

extern "C" void kernel_launch(void* const* d_in, const int* in_sizes, int n_in,
                              void* d_out, int out_size, void* d_ws, size_t ws_size,
                              hipStream_t stream) {
    const float* X  = (const float*)d_in[0];
    const float* Cc = (const float*)d_in[1];
    const float* PA = (const float*)d_in[2];
    const float* PB = (const float*)d_in[3];

    u16* WA = (u16*)d_ws;                          // 512*576*2 bytes (k-major)
    u16* WB = WA + (size_t)N_OUT * D_TOT;          // another 512*576*2

    float* Z  = (float*)d_out;
    const size_t batch = (size_t)in_sizes[0] / N_OUT;   // 131072
    float* LD = Z + batch * N_OUT;

    prep_weights_kernel<<<N_OUT, 256, 0, stream>>>(PA, PB, WA, WB);

    const size_t lds_bytes = (size_t)BM * ROW_BYTES + NWAVES * BM * sizeof(float); // 37376
    const int grid = (int)(batch / BM);            // 4096
    maf_main_kernel<<<grid, 256, lds_bytes, stream>>>(X, Cc, WA, WB, Z, LD);
}